// Round 2
// baseline (1483.416 us; speedup 1.0000x reference)
//
#include <hip/hip_runtime.h>
#include <hip/hip_bf16.h>

// ---------------------------------------------------------------------------
// BasicTransformerBlock (l2-attention x2 + GEGLU FFN), MI355X gfx950
// Round 2: fp32 external I/O (reference dtypes), internal bf16 MFMA GEMMs +
// fp32 VALU flash attention. Residual stream fp32 in workspace.
// ---------------------------------------------------------------------------

typedef short bf16x8 __attribute__((ext_vector_type(8)));
typedef float f32x4 __attribute__((ext_vector_type(4)));
typedef unsigned short u16;
typedef unsigned int u32;

__device__ __forceinline__ float bf2f(u16 u) {
    return __uint_as_float(((u32)u) << 16);
}
__device__ __forceinline__ u16 f2bf(float f) {
    u32 u = __float_as_uint(f);
    u32 rb = ((u >> 16) & 1u) + 0x7fffu;   // round-to-nearest-even
    return (u16)((u + rb) >> 16);
}
__device__ __forceinline__ float gelu_exact(float x) {
    return 0.5f * x * (1.f + erff(x * 0.7071067811865475f));
}

// ---------------------------------------------------------------------------
// fp32 [R][C] -> bf16 [C][R] transpose (weight prep)
__global__ __launch_bounds__(256) void transpose_f32_bf16(const float* __restrict__ in,
                                                          u16* __restrict__ out,
                                                          int R, int C) {
    __shared__ float tile[32][33];
    int bx = blockIdx.x, by = blockIdx.y;
    int t = threadIdx.x;
    int c = t & 31, r0 = (t >> 5) * 4;
#pragma unroll
    for (int i = 0; i < 4; i++)
        tile[r0 + i][c] = in[(size_t)(by * 32 + r0 + i) * C + bx * 32 + c];
    __syncthreads();
#pragma unroll
    for (int i = 0; i < 4; i++)
        out[(size_t)(bx * 32 + r0 + i) * R + by * 32 + c] = f2bf(tile[c][r0 + i]);
}

// ---------------------------------------------------------------------------
// LayerNorm: x fp32 [rows][512] -> out bf16, one block per row
__global__ __launch_bounds__(256) void ln_kernel(const float* __restrict__ x,
                                                 const float* __restrict__ w,
                                                 const float* __restrict__ b,
                                                 u16* __restrict__ out) {
    int row = blockIdx.x, t = threadIdx.x;
    const float* xr = x + (size_t)row * 512;
    float2 v = *(const float2*)(xr + t * 2);
    float s1 = v.x + v.y;
    float s2 = v.x * v.x + v.y * v.y;
#pragma unroll
    for (int m = 1; m < 64; m <<= 1) {
        s1 += __shfl_xor(s1, m);
        s2 += __shfl_xor(s2, m);
    }
    __shared__ float r1[4], r2[4];
    int wave = t >> 6, lane = t & 63;
    if (lane == 0) { r1[wave] = s1; r2[wave] = s2; }
    __syncthreads();
    float tot1 = r1[0] + r1[1] + r1[2] + r1[3];
    float tot2 = r2[0] + r2[1] + r2[2] + r2[3];
    float mu = tot1 * (1.f / 512.f);
    float var = tot2 * (1.f / 512.f) - mu * mu;
    float rs = rsqrtf(var + 1e-5f);
    float2 wv = *(const float2*)(w + t * 2);
    float2 bv = *(const float2*)(b + t * 2);
    float o0 = (v.x - mu) * rs * wv.x + bv.x;
    float o1 = (v.y - mu) * rs * wv.y + bv.y;
    u32 pack = (u32)f2bf(o0) | ((u32)f2bf(o1) << 16);
    *(u32*)(out + (size_t)row * 512 + t * 2) = pack;
}

// ---------------------------------------------------------------------------
// MFMA GEMM: C[M,N] = A[M,K](bf16) * BT[N,K]^T(bf16) + bias(fp32)
// MODE 0: out fp32 | 1: out bf16 | 2: fp32 out = acc + res
template <int MODE>
__global__ __launch_bounds__(256) void gemm64(const u16* __restrict__ A,
                                              const u16* __restrict__ BT,
                                              const float* __restrict__ bias,
                                              const float* __restrict__ res,
                                              float* __restrict__ outf,
                                              u16* __restrict__ outb,
                                              int M, int N, int K) {
    __shared__ u16 As[64][40];   // +8 pad keeps 16B row alignment
    __shared__ u16 Bs[64][40];
    int t = threadIdx.x;
    int m0 = blockIdx.x * 64, n0 = blockIdx.y * 64;
    int wave = t >> 6, lane = t & 63, quad = lane >> 4, l16 = lane & 15;
    int wm = (wave >> 1) * 32, wn = (wave & 1) * 32;
    int sr = t >> 2, sc = (t & 3) * 8;
    f32x4 acc00 = {0.f, 0.f, 0.f, 0.f}, acc01 = {0.f, 0.f, 0.f, 0.f};
    f32x4 acc10 = {0.f, 0.f, 0.f, 0.f}, acc11 = {0.f, 0.f, 0.f, 0.f};
    const u16* Ap = A + (size_t)(m0 + sr) * K + sc;
    const u16* Bp = BT + (size_t)(n0 + sr) * K + sc;
    for (int k0 = 0; k0 < K; k0 += 32) {
        uint4 av = *(const uint4*)(Ap + k0);
        uint4 bv = *(const uint4*)(Bp + k0);
        __syncthreads();
        *(uint4*)&As[sr][sc] = av;
        *(uint4*)&Bs[sr][sc] = bv;
        __syncthreads();
        bf16x8 a0 = *(const bf16x8*)&As[wm + l16][quad * 8];
        bf16x8 a1 = *(const bf16x8*)&As[wm + 16 + l16][quad * 8];
        bf16x8 b0 = *(const bf16x8*)&Bs[wn + l16][quad * 8];
        bf16x8 b1 = *(const bf16x8*)&Bs[wn + 16 + l16][quad * 8];
        acc00 = __builtin_amdgcn_mfma_f32_16x16x32_bf16(a0, b0, acc00, 0, 0, 0);
        acc01 = __builtin_amdgcn_mfma_f32_16x16x32_bf16(a0, b1, acc01, 0, 0, 0);
        acc10 = __builtin_amdgcn_mfma_f32_16x16x32_bf16(a1, b0, acc10, 0, 0, 0);
        acc11 = __builtin_amdgcn_mfma_f32_16x16x32_bf16(a1, b1, acc11, 0, 0, 0);
    }
    // epilogue: C/D layout col=lane&15, row=(lane>>4)*4+reg  [m89 verified]
    int row0 = m0 + wm + quad * 4;
    int colA = n0 + wn + l16;
    int colB = colA + 16;
    float biasA = bias[colA];
    float biasB = bias[colB];
#pragma unroll
    for (int r = 0; r < 4; r++) {
        float v00 = acc00[r] + biasA;
        float v01 = acc01[r] + biasB;
        float v10 = acc10[r] + biasA;
        float v11 = acc11[r] + biasB;
        size_t i00 = (size_t)(row0 + r) * N + colA;
        size_t i01 = (size_t)(row0 + r) * N + colB;
        size_t i10 = (size_t)(row0 + 16 + r) * N + colA;
        size_t i11 = (size_t)(row0 + 16 + r) * N + colB;
        if (MODE == 0) {
            outf[i00] = v00; outf[i01] = v01; outf[i10] = v10; outf[i11] = v11;
        } else if (MODE == 1) {
            outb[i00] = f2bf(v00); outb[i01] = f2bf(v01);
            outb[i10] = f2bf(v10); outb[i11] = f2bf(v11);
        } else {
            outf[i00] = v00 + res[i00]; outf[i01] = v01 + res[i01];
            outf[i10] = v10 + res[i10]; outf[i11] = v11 + res[i11];
        }
    }
}

// ---------------------------------------------------------------------------
// AA[b,h,n] = sum_d q[b,n,h*64+d]^2   (aa layout: [(b*8+h)*2048 + n])
__global__ __launch_bounds__(256) void aa_kernel(const float* __restrict__ q,
                                                 float* __restrict__ aa) {
    int token = blockIdx.x * 4 + (threadIdx.x >> 6);
    int lane = threadIdx.x & 63;
    const float* row = q + (size_t)token * 512 + lane * 8;
    float4 a = *(const float4*)row;
    float4 c = *(const float4*)(row + 4);
    float s = a.x * a.x + a.y * a.y + a.z * a.z + a.w * a.w +
              c.x * c.x + c.y * c.y + c.z * c.z + c.w * c.w;
    s += __shfl_xor(s, 1); s += __shfl_xor(s, 2); s += __shfl_xor(s, 4);
    if ((lane & 7) == 0) {
        int h = lane >> 3;
        int b = token >> 11, n = token & 2047;
        aa[(size_t)(b * 8 + h) * 2048 + n] = s;
    }
}

// ---------------------------------------------------------------------------
// Flash L2-attention (fp32 VALU): logits = (2*q_i.q_j - AA_j)*scale, K=Q
// (AA_i row-constant cancels in softmax.)  Block: (itile, bh), 256 threads;
// thread t handles rows rq*4..+3, cols cq*4..+3 of the 64x64 tile.
__global__ __launch_bounds__(256) void attn_kernel(const float* __restrict__ q,
                                                   const float* __restrict__ v,
                                                   const float* __restrict__ aa,
                                                   u16* __restrict__ out) {
    __shared__ float Qi[64][68];
    __shared__ float QjT[64][68];   // QjT[k][j]; reused as SxT[j][r] for P exchange
    __shared__ float Vj[64][68];
    __shared__ float AAj[64];
    int itile = blockIdx.x, bh = blockIdx.y;
    int b = bh >> 3, h = bh & 7;
    const float* qbh = q + ((size_t)b * 2048) * 512 + h * 64;
    const float* vbh = v + ((size_t)b * 2048) * 512 + h * 64;
    const float* aabh = aa + (size_t)bh * 2048;
    int t = threadIdx.x;
    int rq = t >> 4, cq = t & 15;
    int sr = t >> 2, sc0 = (t & 3) * 16;
    // stage Qi once (synchronized by the first in-loop barrier)
    {
        const float* src = qbh + (size_t)(itile * 64 + sr) * 512 + sc0;
#pragma unroll
        for (int k = 0; k < 4; k++)
            *(float4*)&Qi[sr][sc0 + k * 4] = *(const float4*)(src + k * 4);
    }
    float O[4][4];
    float mrow[4], lrow[4];
#pragma unroll
    for (int i = 0; i < 4; i++) {
        mrow[i] = -1e30f; lrow[i] = 0.f;
#pragma unroll
        for (int e = 0; e < 4; e++) O[i][e] = 0.f;
    }

    for (int j0 = 0; j0 < 2048; j0 += 64) {
        __syncthreads();   // previous iteration fully consumed (also covers Qi stage)
        {
            const float* srcq = qbh + (size_t)(j0 + sr) * 512 + sc0;
            const float* srcv = vbh + (size_t)(j0 + sr) * 512 + sc0;
            float4 a0 = *(const float4*)(srcq);
            float4 a1 = *(const float4*)(srcq + 4);
            float4 a2 = *(const float4*)(srcq + 8);
            float4 a3 = *(const float4*)(srcq + 12);
            QjT[sc0 + 0][sr] = a0.x;  QjT[sc0 + 1][sr] = a0.y;
            QjT[sc0 + 2][sr] = a0.z;  QjT[sc0 + 3][sr] = a0.w;
            QjT[sc0 + 4][sr] = a1.x;  QjT[sc0 + 5][sr] = a1.y;
            QjT[sc0 + 6][sr] = a1.z;  QjT[sc0 + 7][sr] = a1.w;
            QjT[sc0 + 8][sr] = a2.x;  QjT[sc0 + 9][sr] = a2.y;
            QjT[sc0 + 10][sr] = a2.z; QjT[sc0 + 11][sr] = a2.w;
            QjT[sc0 + 12][sr] = a3.x; QjT[sc0 + 13][sr] = a3.y;
            QjT[sc0 + 14][sr] = a3.z; QjT[sc0 + 15][sr] = a3.w;
#pragma unroll
            for (int k = 0; k < 4; k++)
                *(float4*)&Vj[sr][sc0 + k * 4] = *(const float4*)(srcv + k * 4);
            if (t < 64) AAj[t] = aabh[j0 + t];
        }
        __syncthreads();
        // ---- S = Qi . Qj^T  (4x4 per thread, k blocked by 4) ----
        float s[4][4];
#pragma unroll
        for (int i = 0; i < 4; i++)
#pragma unroll
            for (int jj = 0; jj < 4; jj++) s[i][jj] = 0.f;
#pragma unroll 4
        for (int k = 0; k < 64; k += 4) {
            float4 qj0 = *(const float4*)&QjT[k + 0][cq * 4];
            float4 qj1 = *(const float4*)&QjT[k + 1][cq * 4];
            float4 qj2 = *(const float4*)&QjT[k + 2][cq * 4];
            float4 qj3 = *(const float4*)&QjT[k + 3][cq * 4];
#pragma unroll
            for (int i = 0; i < 4; i++) {
                float4 qi = *(const float4*)&Qi[rq * 4 + i][k];
                s[i][0] += qi.x * qj0.x + qi.y * qj1.x + qi.z * qj2.x + qi.w * qj3.x;
                s[i][1] += qi.x * qj0.y + qi.y * qj1.y + qi.z * qj2.y + qi.w * qj3.y;
                s[i][2] += qi.x * qj0.z + qi.y * qj1.z + qi.z * qj2.z + qi.w * qj3.z;
                s[i][3] += qi.x * qj0.w + qi.y * qj1.w + qi.z * qj2.w + qi.w * qj3.w;
            }
        }
        // ---- online softmax (16 lanes share each row group) ----
        float4 aav = *(const float4*)&AAj[cq * 4];
#pragma unroll
        for (int i = 0; i < 4; i++) {
            s[i][0] = (2.f * s[i][0] - aav.x) * 0.125f;
            s[i][1] = (2.f * s[i][1] - aav.y) * 0.125f;
            s[i][2] = (2.f * s[i][2] - aav.z) * 0.125f;
            s[i][3] = (2.f * s[i][3] - aav.w) * 0.125f;
            float tm = fmaxf(fmaxf(s[i][0], s[i][1]), fmaxf(s[i][2], s[i][3]));
            tm = fmaxf(tm, __shfl_xor(tm, 1));
            tm = fmaxf(tm, __shfl_xor(tm, 2));
            tm = fmaxf(tm, __shfl_xor(tm, 4));
            tm = fmaxf(tm, __shfl_xor(tm, 8));
            float mnew = fmaxf(mrow[i], tm);
            float alpha = __expf(mrow[i] - mnew);
            mrow[i] = mnew;
            float ps = 0.f;
#pragma unroll
            for (int jj = 0; jj < 4; jj++) {
                float p = __expf(s[i][jj] - mnew);
                s[i][jj] = p;
                ps += p;
            }
            ps += __shfl_xor(ps, 1); ps += __shfl_xor(ps, 2);
            ps += __shfl_xor(ps, 4); ps += __shfl_xor(ps, 8);
            lrow[i] = lrow[i] * alpha + ps;
#pragma unroll
            for (int e = 0; e < 4; e++) O[i][e] *= alpha;
        }
        __syncthreads();   // all threads done reading QjT
        // P -> SxT (reuse QjT buffer): SxT[col][row]
#pragma unroll
        for (int i = 0; i < 4; i++)
#pragma unroll
            for (int jj = 0; jj < 4; jj++)
                QjT[cq * 4 + jj][rq * 4 + i] = s[i][jj];
        __syncthreads();
        // ---- O += P @ Vj ----
#pragma unroll 4
        for (int jj = 0; jj < 64; jj++) {
            float4 p4 = *(const float4*)&QjT[jj][rq * 4];
            float4 v4 = *(const float4*)&Vj[jj][cq * 4];
            O[0][0] += p4.x * v4.x; O[0][1] += p4.x * v4.y; O[0][2] += p4.x * v4.z; O[0][3] += p4.x * v4.w;
            O[1][0] += p4.y * v4.x; O[1][1] += p4.y * v4.y; O[1][2] += p4.y * v4.z; O[1][3] += p4.y * v4.w;
            O[2][0] += p4.z * v4.x; O[2][1] += p4.z * v4.y; O[2][2] += p4.z * v4.z; O[2][3] += p4.z * v4.w;
            O[3][0] += p4.w * v4.x; O[3][1] += p4.w * v4.y; O[3][2] += p4.w * v4.z; O[3][3] += p4.w * v4.w;
        }
    }
    // epilogue
#pragma unroll
    for (int i = 0; i < 4; i++) {
        float inv = 1.f / lrow[i];
        size_t base = (size_t)(b * 2048 + itile * 64 + rq * 4 + i) * 512 + h * 64 + cq * 4;
#pragma unroll
        for (int e = 0; e < 4; e++)
            out[base + e] = f2bf(O[i][e] * inv);
    }
}

// ---------------------------------------------------------------------------
// GEGLU: g[m,c] = h[m,c] * gelu(h[m,2048+c]),  h [8192][4096] bf16
__global__ __launch_bounds__(256) void geglu_kernel(const u16* __restrict__ h,
                                                    u16* __restrict__ g) {
    size_t i = ((size_t)blockIdx.x * 256 + threadIdx.x) * 4;
    size_t m = i >> 11;
    int c = (int)(i & 2047);
    const u16* p = h + m * 4096 + c;
    uint2 ua = *(const uint2*)p;
    uint2 ug = *(const uint2*)(p + 2048);
    float a0 = bf2f((u16)(ua.x & 0xffff)), a1 = bf2f((u16)(ua.x >> 16));
    float a2 = bf2f((u16)(ua.y & 0xffff)), a3 = bf2f((u16)(ua.y >> 16));
    float g0 = bf2f((u16)(ug.x & 0xffff)), g1 = bf2f((u16)(ug.x >> 16));
    float g2 = bf2f((u16)(ug.y & 0xffff)), g3 = bf2f((u16)(ug.y >> 16));
    float r0 = a0 * gelu_exact(g0);
    float r1 = a1 * gelu_exact(g1);
    float r2 = a2 * gelu_exact(g2);
    float r3 = a3 * gelu_exact(g3);
    uint2 o;
    o.x = (u32)f2bf(r0) | ((u32)f2bf(r1) << 16);
    o.y = (u32)f2bf(r2) | ((u32)f2bf(r3) << 16);
    *(uint2*)(g + m * 2048 + c) = o;
}

// ---------------------------------------------------------------------------
extern "C" void kernel_launch(void* const* d_in, const int* in_sizes, int n_in,
                              void* d_out, int out_size, void* d_ws, size_t ws_size,
                              hipStream_t stream) {
    const float* x      = (const float*)d_in[0];
    const float* sa_w   = (const float*)d_in[1];
    const float* sa_b   = (const float*)d_in[2];
    const float* ca_w   = (const float*)d_in[3];
    const float* ca_b   = (const float*)d_in[4];
    const float* ffn_w  = (const float*)d_in[5];
    const float* ffn_b  = (const float*)d_in[6];
    const float* a1_wq  = (const float*)d_in[7];
    const float* a1_bq  = (const float*)d_in[8];
    const float* a1_wv  = (const float*)d_in[9];
    const float* a1_bv  = (const float*)d_in[10];
    const float* a1_wo  = (const float*)d_in[11];
    const float* a1_bo  = (const float*)d_in[12];
    const float* a2_wq  = (const float*)d_in[13];
    const float* a2_bq  = (const float*)d_in[14];
    const float* a2_wv  = (const float*)d_in[15];
    const float* a2_bv  = (const float*)d_in[16];
    const float* a2_wo  = (const float*)d_in[17];
    const float* a2_bo  = (const float*)d_in[18];
    const float* ff_w1  = (const float*)d_in[19];
    const float* ff_b1  = (const float*)d_in[20];
    const float* ff_w2  = (const float*)d_in[21];
    const float* ff_b2  = (const float*)d_in[22];

    char* ws = (char*)d_ws;
    const size_t MB = 1ull << 20;
    float* x_res   = (float*)(ws);              // 16 MB fp32 residual stream
    u16* xn        = (u16*)(ws + 16 * MB);      // 8 MB normed activations (bf16)
    u16* wT_a1q    = (u16*)(ws + 24 * MB);      // 6 x 0.5 MB transposed bf16 weights
    u16* wT_a1v    = wT_a1q + 262144;
    u16* wT_a1o    = wT_a1q + 2 * 262144;
    u16* wT_a2q    = wT_a1q + 3 * 262144;
    u16* wT_a2v    = wT_a1q + 4 * 262144;
    u16* wT_a2o    = wT_a1q + 5 * 262144;
    u16* wT_ff1    = (u16*)(ws + 27 * MB);      // 4 MB [4096][512]
    u16* wT_ff2    = (u16*)(ws + 31 * MB);      // 2 MB [512][2048]
    // attn-phase buffers (overlap with ffn-phase hbuf)
    float* qf      = (float*)(ws + 34 * MB);    // 16 MB fp32
    float* vf      = (float*)(ws + 50 * MB);    // 16 MB fp32
    float* aab     = (float*)(ws + 66 * MB);    // 256 KB
    u16* attn_o    = (u16*)(ws + 67 * MB);      // 8 MB bf16
    // ffn-phase buffers
    u16* hbuf      = (u16*)(ws + 34 * MB);      // 64 MB [8192][4096] bf16
    u16* gbuf      = (u16*)(ws + 98 * MB);      // 32 MB [8192][2048] bf16

    (void)in_sizes; (void)n_in; (void)out_size; (void)ws_size;

    // weight transposes (fp32 -> bf16 [N][K])
    transpose_f32_bf16<<<dim3(16, 16), 256, 0, stream>>>(a1_wq, wT_a1q, 512, 512);
    transpose_f32_bf16<<<dim3(16, 16), 256, 0, stream>>>(a1_wv, wT_a1v, 512, 512);
    transpose_f32_bf16<<<dim3(16, 16), 256, 0, stream>>>(a1_wo, wT_a1o, 512, 512);
    transpose_f32_bf16<<<dim3(16, 16), 256, 0, stream>>>(a2_wq, wT_a2q, 512, 512);
    transpose_f32_bf16<<<dim3(16, 16), 256, 0, stream>>>(a2_wv, wT_a2v, 512, 512);
    transpose_f32_bf16<<<dim3(16, 16), 256, 0, stream>>>(a2_wo, wT_a2o, 512, 512);
    transpose_f32_bf16<<<dim3(128, 16), 256, 0, stream>>>(ff_w1, wT_ff1, 512, 4096);
    transpose_f32_bf16<<<dim3(16, 64), 256, 0, stream>>>(ff_w2, wT_ff2, 2048, 512);

    // === attention 1 (self) ===
    ln_kernel<<<8192, 256, 0, stream>>>(x, sa_w, sa_b, xn);
    gemm64<0><<<dim3(128, 8), 256, 0, stream>>>(xn, wT_a1q, a1_bq, nullptr, qf, nullptr, 8192, 512, 512);
    gemm64<0><<<dim3(128, 8), 256, 0, stream>>>(xn, wT_a1v, a1_bv, nullptr, vf, nullptr, 8192, 512, 512);
    aa_kernel<<<2048, 256, 0, stream>>>(qf, aab);
    attn_kernel<<<dim3(32, 32), 256, 0, stream>>>(qf, vf, aab, attn_o);
    gemm64<2><<<dim3(128, 8), 256, 0, stream>>>(attn_o, wT_a1o, a1_bo, x, x_res, nullptr, 8192, 512, 512);

    // === attention 2 ("cross", k=q, v from x) ===
    ln_kernel<<<8192, 256, 0, stream>>>(x_res, ca_w, ca_b, xn);
    gemm64<0><<<dim3(128, 8), 256, 0, stream>>>(xn, wT_a2q, a2_bq, nullptr, qf, nullptr, 8192, 512, 512);
    gemm64<0><<<dim3(128, 8), 256, 0, stream>>>(xn, wT_a2v, a2_bv, nullptr, vf, nullptr, 8192, 512, 512);
    aa_kernel<<<2048, 256, 0, stream>>>(qf, aab);
    attn_kernel<<<dim3(32, 32), 256, 0, stream>>>(qf, vf, aab, attn_o);
    gemm64<2><<<dim3(128, 8), 256, 0, stream>>>(attn_o, wT_a2o, a2_bo, x_res, x_res, nullptr, 8192, 512, 512);

    // === GEGLU FFN ===
    ln_kernel<<<8192, 256, 0, stream>>>(x_res, ffn_w, ffn_b, xn);
    gemm64<1><<<dim3(128, 64), 256, 0, stream>>>(xn, wT_ff1, ff_b1, nullptr, nullptr, hbuf, 8192, 4096, 512);
    geglu_kernel<<<16384, 256, 0, stream>>>(hbuf, gbuf);
    gemm64<2><<<dim3(128, 8), 256, 0, stream>>>(gbuf, wT_ff2, ff_b2, x_res, (float*)d_out, nullptr, 8192, 512, 2048);
}

// Round 3
// 608.157 us; speedup vs baseline: 2.4392x; 2.4392x over previous
//
#include <hip/hip_runtime.h>
#include <hip/hip_bf16.h>

// ---------------------------------------------------------------------------
// BasicTransformerBlock (l2-attention x2 + GEGLU FFN), MI355X gfx950
// Round 3: MFMA flash attention (K=Q trick: QK^T needs no transpose),
// head-major bf16 q/v, wave-local softmax + P round-trip.
// ---------------------------------------------------------------------------

typedef short bf16x8 __attribute__((ext_vector_type(8)));
typedef float f32x4 __attribute__((ext_vector_type(4)));
typedef unsigned short u16;
typedef unsigned int u32;

__device__ __forceinline__ float bf2f(u16 u) {
    return __uint_as_float(((u32)u) << 16);
}
__device__ __forceinline__ u16 f2bf(float f) {
    u32 u = __float_as_uint(f);
    u32 rb = ((u >> 16) & 1u) + 0x7fffu;   // round-to-nearest-even
    return (u16)((u + rb) >> 16);
}
__device__ __forceinline__ float gelu_exact(float x) {
    return 0.5f * x * (1.f + erff(x * 0.7071067811865475f));
}

// ---------------------------------------------------------------------------
// fp32 [R][C] -> bf16 [C][R] transpose (weight prep)
__global__ __launch_bounds__(256) void transpose_f32_bf16(const float* __restrict__ in,
                                                          u16* __restrict__ out,
                                                          int R, int C) {
    __shared__ float tile[32][33];
    int bx = blockIdx.x, by = blockIdx.y;
    int t = threadIdx.x;
    int c = t & 31, r0 = (t >> 5) * 4;
#pragma unroll
    for (int i = 0; i < 4; i++)
        tile[r0 + i][c] = in[(size_t)(by * 32 + r0 + i) * C + bx * 32 + c];
    __syncthreads();
#pragma unroll
    for (int i = 0; i < 4; i++)
        out[(size_t)(bx * 32 + r0 + i) * R + by * 32 + c] = f2bf(tile[c][r0 + i]);
}

// ---------------------------------------------------------------------------
// LayerNorm: x fp32 [rows][512] -> out bf16, one block per row
__global__ __launch_bounds__(256) void ln_kernel(const float* __restrict__ x,
                                                 const float* __restrict__ w,
                                                 const float* __restrict__ b,
                                                 u16* __restrict__ out) {
    int row = blockIdx.x, t = threadIdx.x;
    const float* xr = x + (size_t)row * 512;
    float2 v = *(const float2*)(xr + t * 2);
    float s1 = v.x + v.y;
    float s2 = v.x * v.x + v.y * v.y;
#pragma unroll
    for (int m = 1; m < 64; m <<= 1) {
        s1 += __shfl_xor(s1, m);
        s2 += __shfl_xor(s2, m);
    }
    __shared__ float r1[4], r2[4];
    int wave = t >> 6, lane = t & 63;
    if (lane == 0) { r1[wave] = s1; r2[wave] = s2; }
    __syncthreads();
    float tot1 = r1[0] + r1[1] + r1[2] + r1[3];
    float tot2 = r2[0] + r2[1] + r2[2] + r2[3];
    float mu = tot1 * (1.f / 512.f);
    float var = tot2 * (1.f / 512.f) - mu * mu;
    float rs = rsqrtf(var + 1e-5f);
    float2 wv = *(const float2*)(w + t * 2);
    float2 bv = *(const float2*)(b + t * 2);
    float o0 = (v.x - mu) * rs * wv.x + bv.x;
    float o1 = (v.y - mu) * rs * wv.y + bv.y;
    u32 pack = (u32)f2bf(o0) | ((u32)f2bf(o1) << 16);
    *(u32*)(out + (size_t)row * 512 + t * 2) = pack;
}

// ---------------------------------------------------------------------------
// MFMA GEMM: C[M,N] = A[M,K](bf16) * BT[N,K]^T(bf16) + bias(fp32)
// MODE 0: fp32 | 1: bf16 | 2: fp32 = acc+res | 4: bf16 head-major [bh][2048][64]
template <int MODE>
__global__ __launch_bounds__(256) void gemm64(const u16* __restrict__ A,
                                              const u16* __restrict__ BT,
                                              const float* __restrict__ bias,
                                              const float* __restrict__ res,
                                              float* __restrict__ outf,
                                              u16* __restrict__ outb,
                                              int M, int N, int K) {
    __shared__ u16 As[64][40];
    __shared__ u16 Bs[64][40];
    int t = threadIdx.x;
    int m0 = blockIdx.x * 64, n0 = blockIdx.y * 64;
    int wave = t >> 6, lane = t & 63, quad = lane >> 4, l16 = lane & 15;
    int wm = (wave >> 1) * 32, wn = (wave & 1) * 32;
    int sr = t >> 2, sc = (t & 3) * 8;
    f32x4 acc00 = {0.f, 0.f, 0.f, 0.f}, acc01 = {0.f, 0.f, 0.f, 0.f};
    f32x4 acc10 = {0.f, 0.f, 0.f, 0.f}, acc11 = {0.f, 0.f, 0.f, 0.f};
    const u16* Ap = A + (size_t)(m0 + sr) * K + sc;
    const u16* Bp = BT + (size_t)(n0 + sr) * K + sc;
    for (int k0 = 0; k0 < K; k0 += 32) {
        uint4 av = *(const uint4*)(Ap + k0);
        uint4 bv = *(const uint4*)(Bp + k0);
        __syncthreads();
        *(uint4*)&As[sr][sc] = av;
        *(uint4*)&Bs[sr][sc] = bv;
        __syncthreads();
        bf16x8 a0 = *(const bf16x8*)&As[wm + l16][quad * 8];
        bf16x8 a1 = *(const bf16x8*)&As[wm + 16 + l16][quad * 8];
        bf16x8 b0 = *(const bf16x8*)&Bs[wn + l16][quad * 8];
        bf16x8 b1 = *(const bf16x8*)&Bs[wn + 16 + l16][quad * 8];
        acc00 = __builtin_amdgcn_mfma_f32_16x16x32_bf16(a0, b0, acc00, 0, 0, 0);
        acc01 = __builtin_amdgcn_mfma_f32_16x16x32_bf16(a0, b1, acc01, 0, 0, 0);
        acc10 = __builtin_amdgcn_mfma_f32_16x16x32_bf16(a1, b0, acc10, 0, 0, 0);
        acc11 = __builtin_amdgcn_mfma_f32_16x16x32_bf16(a1, b1, acc11, 0, 0, 0);
    }
    int row0 = m0 + wm + quad * 4;
    int colA = n0 + wn + l16;
    int colB = colA + 16;
    float biasA = bias[colA];
    float biasB = bias[colB];
#pragma unroll
    for (int r = 0; r < 4; r++) {
        float v00 = acc00[r] + biasA;
        float v01 = acc01[r] + biasB;
        float v10 = acc10[r] + biasA;
        float v11 = acc11[r] + biasB;
        int rA = row0 + r, rB = row0 + 16 + r;
        if (MODE == 4) {
            // head-major: [(b*8 + h)][n][d], h=col>>6, d=col&63, b=row>>11, n=row&2047
            size_t i00 = ((size_t)((rA >> 11) * 8 + (colA >> 6)) * 2048 + (rA & 2047)) * 64 + (colA & 63);
            size_t i01 = ((size_t)((rA >> 11) * 8 + (colB >> 6)) * 2048 + (rA & 2047)) * 64 + (colB & 63);
            size_t i10 = ((size_t)((rB >> 11) * 8 + (colA >> 6)) * 2048 + (rB & 2047)) * 64 + (colA & 63);
            size_t i11 = ((size_t)((rB >> 11) * 8 + (colB >> 6)) * 2048 + (rB & 2047)) * 64 + (colB & 63);
            outb[i00] = f2bf(v00); outb[i01] = f2bf(v01);
            outb[i10] = f2bf(v10); outb[i11] = f2bf(v11);
        } else {
            size_t i00 = (size_t)rA * N + colA;
            size_t i01 = (size_t)rA * N + colB;
            size_t i10 = (size_t)rB * N + colA;
            size_t i11 = (size_t)rB * N + colB;
            if (MODE == 0) {
                outf[i00] = v00; outf[i01] = v01; outf[i10] = v10; outf[i11] = v11;
            } else if (MODE == 1) {
                outb[i00] = f2bf(v00); outb[i01] = f2bf(v01);
                outb[i10] = f2bf(v10); outb[i11] = f2bf(v11);
            } else {
                outf[i00] = v00 + res[i00]; outf[i01] = v01 + res[i01];
                outf[i10] = v10 + res[i10]; outf[i11] = v11 + res[i11];
            }
        }
    }
}

// ---------------------------------------------------------------------------
// AA[tok] = sum_d q[tok][d]^2, q head-major bf16 [32*2048][64]
__global__ __launch_bounds__(256) void aa_kernel(const u16* __restrict__ q,
                                                 float* __restrict__ aa) {
    int t = threadIdx.x;
    int tok = blockIdx.x * 32 + (t >> 3);
    int l8 = t & 7;
    const u16* row = q + (size_t)tok * 64 + l8 * 8;
    uint4 u = *(const uint4*)row;
    u32 c[4] = {u.x, u.y, u.z, u.w};
    float s = 0.f;
#pragma unroll
    for (int k = 0; k < 4; k++) {
        float a = bf2f((u16)(c[k] & 0xffff));
        float b = bf2f((u16)(c[k] >> 16));
        s += a * a + b * b;
    }
    s += __shfl_xor(s, 1); s += __shfl_xor(s, 2); s += __shfl_xor(s, 4);
    if (l8 == 0) aa[tok] = s;
}

// ---------------------------------------------------------------------------
// MFMA flash L2-attention. q,v head-major bf16 [bh][2048][64].
// logits = (2*q_i.q_j - AA_j)*scale  (AA_i cancels in softmax).
// Block (itile, bh), 4 waves; wave w owns i-rows w*16..+15 of the 64-row tile.
__global__ __launch_bounds__(256) void attn_mfma(const u16* __restrict__ q,
                                                 const u16* __restrict__ v,
                                                 const float* __restrict__ aa,
                                                 u16* __restrict__ out) {
    __shared__ u16 Qj[64][72];   // j-token rows (B operand for S; natural layout)
    __shared__ u16 VT[64][72];   // V^T: [d][j]   (B operand for PV)
    __shared__ u16 Pl[64][72];   // P rows (A operand for PV; wave-local regions)
    __shared__ float AAs[64];
    int itile = blockIdx.x, bh = blockIdx.y;
    const u16* qb = q + (size_t)bh * 2048 * 64;
    const u16* vb = v + (size_t)bh * 2048 * 64;
    const float* aab = aa + (size_t)bh * 2048;
    int t = threadIdx.x;
    int wave = t >> 6, lane = t & 63, quad = lane >> 4, l16 = lane & 15;
    // Qi A-fragments (fixed for whole j-loop): row = i, k = d
    int irow = itile * 64 + wave * 16 + l16;
    bf16x8 qa0 = *(const bf16x8*)(qb + (size_t)irow * 64 + quad * 8);
    bf16x8 qa1 = *(const bf16x8*)(qb + (size_t)irow * 64 + 32 + quad * 8);
    f32x4 O0 = {0.f,0.f,0.f,0.f}, O1 = {0.f,0.f,0.f,0.f};
    f32x4 O2 = {0.f,0.f,0.f,0.f}, O3 = {0.f,0.f,0.f,0.f};
    float mrow[4], lrow[4];
#pragma unroll
    for (int r = 0; r < 4; r++) { mrow[r] = -1e30f; lrow[r] = 0.f; }
    // staging coords
    int sr = t >> 2, sc = (t & 3) * 16;         // Qj: 4 threads/row, 32B each
    int jp = t & 31, dc = t >> 5;               // VT: pair-transpose

    for (int j0 = 0; j0 < 2048; j0 += 64) {
        __syncthreads();   // prior iteration's Qj/VT reads complete
        {   // stage Qj rows
            const u16* src = qb + (size_t)(j0 + sr) * 64 + sc;
            uint4 a = *(const uint4*)src;
            uint4 b = *(const uint4*)(src + 8);
            *(uint4*)&Qj[sr][sc] = a;
            *(uint4*)&Qj[sr][sc + 8] = b;
        }
        {   // stage V^T: thread covers rows j0+2jp, j0+2jp+1, d = dc*8..+7
            const u16* r0 = vb + (size_t)(j0 + 2 * jp) * 64 + dc * 8;
            uint4 u0 = *(const uint4*)r0;
            uint4 u1 = *(const uint4*)(r0 + 64);
            u32 c0[4] = {u0.x, u0.y, u0.z, u0.w};
            u32 c1[4] = {u1.x, u1.y, u1.z, u1.w};
#pragma unroll
            for (int k = 0; k < 8; k++) {
                u32 lo = (k & 1) ? (c0[k >> 1] >> 16) : (c0[k >> 1] & 0xffff);
                u32 hi = (k & 1) ? (c1[k >> 1] >> 16) : (c1[k >> 1] & 0xffff);
                *(u32*)&VT[dc * 8 + k][2 * jp] = lo | (hi << 16);
            }
        }
        if (t < 64) AAs[t] = aab[j0 + t] * 0.125f;
        __syncthreads();
        // ---- S = Qi . Qj^T via MFMA: 4 col-tiles x 2 k-steps ----
        f32x4 s0 = {0.f,0.f,0.f,0.f}, s1 = {0.f,0.f,0.f,0.f};
        f32x4 s2 = {0.f,0.f,0.f,0.f}, s3 = {0.f,0.f,0.f,0.f};
        {
            bf16x8 b0 = *(const bf16x8*)&Qj[l16][quad * 8];
            bf16x8 b0b = *(const bf16x8*)&Qj[l16][32 + quad * 8];
            s0 = __builtin_amdgcn_mfma_f32_16x16x32_bf16(qa0, b0, s0, 0, 0, 0);
            s0 = __builtin_amdgcn_mfma_f32_16x16x32_bf16(qa1, b0b, s0, 0, 0, 0);
            bf16x8 b1 = *(const bf16x8*)&Qj[16 + l16][quad * 8];
            bf16x8 b1b = *(const bf16x8*)&Qj[16 + l16][32 + quad * 8];
            s1 = __builtin_amdgcn_mfma_f32_16x16x32_bf16(qa0, b1, s1, 0, 0, 0);
            s1 = __builtin_amdgcn_mfma_f32_16x16x32_bf16(qa1, b1b, s1, 0, 0, 0);
            bf16x8 b2 = *(const bf16x8*)&Qj[32 + l16][quad * 8];
            bf16x8 b2b = *(const bf16x8*)&Qj[32 + l16][32 + quad * 8];
            s2 = __builtin_amdgcn_mfma_f32_16x16x32_bf16(qa0, b2, s2, 0, 0, 0);
            s2 = __builtin_amdgcn_mfma_f32_16x16x32_bf16(qa1, b2b, s2, 0, 0, 0);
            bf16x8 b3 = *(const bf16x8*)&Qj[48 + l16][quad * 8];
            bf16x8 b3b = *(const bf16x8*)&Qj[48 + l16][32 + quad * 8];
            s3 = __builtin_amdgcn_mfma_f32_16x16x32_bf16(qa0, b3, s3, 0, 0, 0);
            s3 = __builtin_amdgcn_mfma_f32_16x16x32_bf16(qa1, b3b, s3, 0, 0, 0);
        }
        // logits = acc*0.25 - AAs[col];  C-layout: col = ct*16+l16, row = quad*4+r
        float aa0 = AAs[l16], aa1 = AAs[16 + l16], aa2 = AAs[32 + l16], aa3 = AAs[48 + l16];
        float alpha[4];
#pragma unroll
        for (int r = 0; r < 4; r++) {
            float e0 = s0[r] * 0.25f - aa0;
            float e1 = s1[r] * 0.25f - aa1;
            float e2 = s2[r] * 0.25f - aa2;
            float e3 = s3[r] * 0.25f - aa3;
            float tm = fmaxf(fmaxf(e0, e1), fmaxf(e2, e3));
            tm = fmaxf(tm, __shfl_xor(tm, 1));
            tm = fmaxf(tm, __shfl_xor(tm, 2));
            tm = fmaxf(tm, __shfl_xor(tm, 4));
            tm = fmaxf(tm, __shfl_xor(tm, 8));
            float mnew = fmaxf(mrow[r], tm);
            alpha[r] = __expf(mrow[r] - mnew);
            mrow[r] = mnew;
            float p0 = __expf(e0 - mnew);
            float p1 = __expf(e1 - mnew);
            float p2 = __expf(e2 - mnew);
            float p3 = __expf(e3 - mnew);
            s0[r] = p0; s1[r] = p1; s2[r] = p2; s3[r] = p3;
            float ps = p0 + p1 + p2 + p3;
            ps += __shfl_xor(ps, 1); ps += __shfl_xor(ps, 2);
            ps += __shfl_xor(ps, 4); ps += __shfl_xor(ps, 8);
            lrow[r] = lrow[r] * alpha[r] + ps;
            O0[r] *= alpha[r]; O1[r] *= alpha[r]; O2[r] *= alpha[r]; O3[r] *= alpha[r];
        }
        // ---- P (C-layout) -> Pl rows (A-layout), wave-local ----
#pragma unroll
        for (int r = 0; r < 4; r++) {
            int prow = wave * 16 + quad * 4 + r;
            Pl[prow][l16] = f2bf(s0[r]);
            Pl[prow][16 + l16] = f2bf(s1[r]);
            Pl[prow][32 + l16] = f2bf(s2[r]);
            Pl[prow][48 + l16] = f2bf(s3[r]);
        }
        // ---- O += P @ V : A = Pl (own rows), B = VT ----
        {
            bf16x8 pa0 = *(const bf16x8*)&Pl[wave * 16 + l16][quad * 8];
            bf16x8 pa1 = *(const bf16x8*)&Pl[wave * 16 + l16][32 + quad * 8];
            bf16x8 vb0 = *(const bf16x8*)&VT[l16][quad * 8];
            bf16x8 vb0b = *(const bf16x8*)&VT[l16][32 + quad * 8];
            O0 = __builtin_amdgcn_mfma_f32_16x16x32_bf16(pa0, vb0, O0, 0, 0, 0);
            O0 = __builtin_amdgcn_mfma_f32_16x16x32_bf16(pa1, vb0b, O0, 0, 0, 0);
            bf16x8 vb1 = *(const bf16x8*)&VT[16 + l16][quad * 8];
            bf16x8 vb1b = *(const bf16x8*)&VT[16 + l16][32 + quad * 8];
            O1 = __builtin_amdgcn_mfma_f32_16x16x32_bf16(pa0, vb1, O1, 0, 0, 0);
            O1 = __builtin_amdgcn_mfma_f32_16x16x32_bf16(pa1, vb1b, O1, 0, 0, 0);
            bf16x8 vb2 = *(const bf16x8*)&VT[32 + l16][quad * 8];
            bf16x8 vb2b = *(const bf16x8*)&VT[32 + l16][32 + quad * 8];
            O2 = __builtin_amdgcn_mfma_f32_16x16x32_bf16(pa0, vb2, O2, 0, 0, 0);
            O2 = __builtin_amdgcn_mfma_f32_16x16x32_bf16(pa1, vb2b, O2, 0, 0, 0);
            bf16x8 vb3 = *(const bf16x8*)&VT[48 + l16][quad * 8];
            bf16x8 vb3b = *(const bf16x8*)&VT[48 + l16][32 + quad * 8];
            O3 = __builtin_amdgcn_mfma_f32_16x16x32_bf16(pa0, vb3, O3, 0, 0, 0);
            O3 = __builtin_amdgcn_mfma_f32_16x16x32_bf16(pa1, vb3b, O3, 0, 0, 0);
        }
    }
    // epilogue: out [8192][512] bf16, row = b*2048 + i, col = h*64 + d
    int b = bh >> 3, h = bh & 7;
#pragma unroll
    for (int r = 0; r < 4; r++) {
        float inv = 1.f / lrow[r];
        size_t row = (size_t)(b * 2048 + itile * 64 + wave * 16 + quad * 4 + r);
        u16* o = out + row * 512 + h * 64 + l16;
        o[0] = f2bf(O0[r] * inv);
        o[16] = f2bf(O1[r] * inv);
        o[32] = f2bf(O2[r] * inv);
        o[48] = f2bf(O3[r] * inv);
    }
}

// ---------------------------------------------------------------------------
// GEGLU: g[m,c] = h[m,c] * gelu(h[m,2048+c]),  h [8192][4096] bf16
__global__ __launch_bounds__(256) void geglu_kernel(const u16* __restrict__ h,
                                                    u16* __restrict__ g) {
    size_t i = ((size_t)blockIdx.x * 256 + threadIdx.x) * 4;
    size_t m = i >> 11;
    int c = (int)(i & 2047);
    const u16* p = h + m * 4096 + c;
    uint2 ua = *(const uint2*)p;
    uint2 ug = *(const uint2*)(p + 2048);
    float a0 = bf2f((u16)(ua.x & 0xffff)), a1 = bf2f((u16)(ua.x >> 16));
    float a2 = bf2f((u16)(ua.y & 0xffff)), a3 = bf2f((u16)(ua.y >> 16));
    float g0 = bf2f((u16)(ug.x & 0xffff)), g1 = bf2f((u16)(ug.x >> 16));
    float g2 = bf2f((u16)(ug.y & 0xffff)), g3 = bf2f((u16)(ug.y >> 16));
    float r0 = a0 * gelu_exact(g0);
    float r1 = a1 * gelu_exact(g1);
    float r2 = a2 * gelu_exact(g2);
    float r3 = a3 * gelu_exact(g3);
    uint2 o;
    o.x = (u32)f2bf(r0) | ((u32)f2bf(r1) << 16);
    o.y = (u32)f2bf(r2) | ((u32)f2bf(r3) << 16);
    *(uint2*)(g + m * 2048 + c) = o;
}

// ---------------------------------------------------------------------------
extern "C" void kernel_launch(void* const* d_in, const int* in_sizes, int n_in,
                              void* d_out, int out_size, void* d_ws, size_t ws_size,
                              hipStream_t stream) {
    const float* x      = (const float*)d_in[0];
    const float* sa_w   = (const float*)d_in[1];
    const float* sa_b   = (const float*)d_in[2];
    const float* ca_w   = (const float*)d_in[3];
    const float* ca_b   = (const float*)d_in[4];
    const float* ffn_w  = (const float*)d_in[5];
    const float* ffn_b  = (const float*)d_in[6];
    const float* a1_wq  = (const float*)d_in[7];
    const float* a1_bq  = (const float*)d_in[8];
    const float* a1_wv  = (const float*)d_in[9];
    const float* a1_bv  = (const float*)d_in[10];
    const float* a1_wo  = (const float*)d_in[11];
    const float* a1_bo  = (const float*)d_in[12];
    const float* a2_wq  = (const float*)d_in[13];
    const float* a2_bq  = (const float*)d_in[14];
    const float* a2_wv  = (const float*)d_in[15];
    const float* a2_bv  = (const float*)d_in[16];
    const float* a2_wo  = (const float*)d_in[17];
    const float* a2_bo  = (const float*)d_in[18];
    const float* ff_w1  = (const float*)d_in[19];
    const float* ff_b1  = (const float*)d_in[20];
    const float* ff_w2  = (const float*)d_in[21];
    const float* ff_b2  = (const float*)d_in[22];

    char* ws = (char*)d_ws;
    const size_t MB = 1ull << 20;
    float* x_res   = (float*)(ws);              // 16 MB fp32 residual stream
    u16* xn        = (u16*)(ws + 16 * MB);      // 8 MB normed activations (bf16)
    u16* wT_a1q    = (u16*)(ws + 24 * MB);      // 6 x 0.5 MB transposed bf16 weights
    u16* wT_a1v    = wT_a1q + 262144;
    u16* wT_a1o    = wT_a1q + 2 * 262144;
    u16* wT_a2q    = wT_a1q + 3 * 262144;
    u16* wT_a2v    = wT_a1q + 4 * 262144;
    u16* wT_a2o    = wT_a1q + 5 * 262144;
    u16* wT_ff1    = (u16*)(ws + 27 * MB);      // 4 MB [4096][512]
    u16* wT_ff2    = (u16*)(ws + 31 * MB);      // 2 MB [512][2048]
    // attn-phase buffers (overlap with ffn-phase hbuf)
    u16* qhm       = (u16*)(ws + 34 * MB);      // 8 MB bf16 head-major [32][2048][64]
    u16* vhm       = (u16*)(ws + 42 * MB);      // 8 MB bf16 head-major
    float* aab     = (float*)(ws + 50 * MB);    // 256 KB
    u16* attn_o    = (u16*)(ws + 51 * MB);      // 8 MB bf16 [8192][512]
    // ffn-phase buffers
    u16* hbuf      = (u16*)(ws + 34 * MB);      // 64 MB [8192][4096] bf16
    u16* gbuf      = (u16*)(ws + 98 * MB);      // 32 MB [8192][2048] bf16

    (void)in_sizes; (void)n_in; (void)out_size; (void)ws_size;

    // weight transposes (fp32 -> bf16 [N][K])
    transpose_f32_bf16<<<dim3(16, 16), 256, 0, stream>>>(a1_wq, wT_a1q, 512, 512);
    transpose_f32_bf16<<<dim3(16, 16), 256, 0, stream>>>(a1_wv, wT_a1v, 512, 512);
    transpose_f32_bf16<<<dim3(16, 16), 256, 0, stream>>>(a1_wo, wT_a1o, 512, 512);
    transpose_f32_bf16<<<dim3(16, 16), 256, 0, stream>>>(a2_wq, wT_a2q, 512, 512);
    transpose_f32_bf16<<<dim3(16, 16), 256, 0, stream>>>(a2_wv, wT_a2v, 512, 512);
    transpose_f32_bf16<<<dim3(16, 16), 256, 0, stream>>>(a2_wo, wT_a2o, 512, 512);
    transpose_f32_bf16<<<dim3(128, 16), 256, 0, stream>>>(ff_w1, wT_ff1, 512, 4096);
    transpose_f32_bf16<<<dim3(16, 64), 256, 0, stream>>>(ff_w2, wT_ff2, 2048, 512);

    // === attention 1 (self) ===
    ln_kernel<<<8192, 256, 0, stream>>>(x, sa_w, sa_b, xn);
    gemm64<4><<<dim3(128, 8), 256, 0, stream>>>(xn, wT_a1q, a1_bq, nullptr, nullptr, qhm, 8192, 512, 512);
    gemm64<4><<<dim3(128, 8), 256, 0, stream>>>(xn, wT_a1v, a1_bv, nullptr, nullptr, vhm, 8192, 512, 512);
    aa_kernel<<<2048, 256, 0, stream>>>(qhm, aab);
    attn_mfma<<<dim3(32, 32), 256, 0, stream>>>(qhm, vhm, aab, attn_o);
    gemm64<2><<<dim3(128, 8), 256, 0, stream>>>(attn_o, wT_a1o, a1_bo, x, x_res, nullptr, 8192, 512, 512);

    // === attention 2 ("cross", k=q, v from x) ===
    ln_kernel<<<8192, 256, 0, stream>>>(x_res, ca_w, ca_b, xn);
    gemm64<4><<<dim3(128, 8), 256, 0, stream>>>(xn, wT_a2q, a2_bq, nullptr, nullptr, qhm, 8192, 512, 512);
    gemm64<4><<<dim3(128, 8), 256, 0, stream>>>(xn, wT_a2v, a2_bv, nullptr, nullptr, vhm, 8192, 512, 512);
    aa_kernel<<<2048, 256, 0, stream>>>(qhm, aab);
    attn_mfma<<<dim3(32, 32), 256, 0, stream>>>(qhm, vhm, aab, attn_o);
    gemm64<2><<<dim3(128, 8), 256, 0, stream>>>(attn_o, wT_a2o, a2_bo, x_res, x_res, nullptr, 8192, 512, 512);

    // === GEGLU FFN ===
    ln_kernel<<<8192, 256, 0, stream>>>(x_res, ffn_w, ffn_b, xn);
    gemm64<1><<<dim3(128, 64), 256, 0, stream>>>(xn, wT_ff1, ff_b1, nullptr, nullptr, hbuf, 8192, 4096, 512);
    geglu_kernel<<<16384, 256, 0, stream>>>(hbuf, gbuf);
    gemm64<2><<<dim3(128, 8), 256, 0, stream>>>(gbuf, wT_ff2, ff_b2, x_res, (float*)d_out, nullptr, 8192, 512, 2048);
}

// Round 4
// 495.678 us; speedup vs baseline: 2.9927x; 1.2269x over previous
//
#include <hip/hip_runtime.h>
#include <hip/hip_bf16.h>

// ---------------------------------------------------------------------------
// BasicTransformerBlock (l2-attention x2 + GEGLU FFN), MI355X gfx950
// Round 4: m97-style 128x128 GEMM w/ global_load_lds(16B) + fused q|v proj;
// attention: static-max softmax (row max == 0 since K=Q), wave-local P buffer,
// 2 barriers/iter, no per-iter shuffles.
// ---------------------------------------------------------------------------

typedef short bf16x8 __attribute__((ext_vector_type(8)));
typedef float f32x4 __attribute__((ext_vector_type(4)));
typedef unsigned short u16;
typedef unsigned int u32;

__device__ __forceinline__ float bf2f(u16 u) {
    return __uint_as_float(((u32)u) << 16);
}
__device__ __forceinline__ u16 f2bf(float f) {
    u32 u = __float_as_uint(f);
    u32 rb = ((u >> 16) & 1u) + 0x7fffu;   // round-to-nearest-even
    return (u16)((u + rb) >> 16);
}
__device__ __forceinline__ float gelu_exact(float x) {
    return 0.5f * x * (1.f + erff(x * 0.7071067811865475f));
}
__device__ __forceinline__ void gl2lds16(const u16* g, u16* l) {
    __builtin_amdgcn_global_load_lds(
        (const __attribute__((address_space(1))) void*)(unsigned long long)(uintptr_t)g,
        (__attribute__((address_space(3))) void*)(unsigned long long)(uintptr_t)l,
        16, 0, 0);
}

// ---------------------------------------------------------------------------
// fp32 [R][C] -> bf16 [C][R] transpose (weight prep)
__global__ __launch_bounds__(256) void transpose_f32_bf16(const float* __restrict__ in,
                                                          u16* __restrict__ out,
                                                          int R, int C) {
    __shared__ float tile[32][33];
    int bx = blockIdx.x, by = blockIdx.y;
    int t = threadIdx.x;
    int c = t & 31, r0 = (t >> 5) * 4;
#pragma unroll
    for (int i = 0; i < 4; i++)
        tile[r0 + i][c] = in[(size_t)(by * 32 + r0 + i) * C + bx * 32 + c];
    __syncthreads();
#pragma unroll
    for (int i = 0; i < 4; i++)
        out[(size_t)(bx * 32 + r0 + i) * R + by * 32 + c] = f2bf(tile[c][r0 + i]);
}

// ---------------------------------------------------------------------------
// LayerNorm: x fp32 [rows][512] -> out bf16, one block per row
__global__ __launch_bounds__(256) void ln_kernel(const float* __restrict__ x,
                                                 const float* __restrict__ w,
                                                 const float* __restrict__ b,
                                                 u16* __restrict__ out) {
    int row = blockIdx.x, t = threadIdx.x;
    const float* xr = x + (size_t)row * 512;
    float2 v = *(const float2*)(xr + t * 2);
    float s1 = v.x + v.y;
    float s2 = v.x * v.x + v.y * v.y;
#pragma unroll
    for (int m = 1; m < 64; m <<= 1) {
        s1 += __shfl_xor(s1, m);
        s2 += __shfl_xor(s2, m);
    }
    __shared__ float r1[4], r2[4];
    int wave = t >> 6, lane = t & 63;
    if (lane == 0) { r1[wave] = s1; r2[wave] = s2; }
    __syncthreads();
    float tot1 = r1[0] + r1[1] + r1[2] + r1[3];
    float tot2 = r2[0] + r2[1] + r2[2] + r2[3];
    float mu = tot1 * (1.f / 512.f);
    float var = tot2 * (1.f / 512.f) - mu * mu;
    float rs = rsqrtf(var + 1e-5f);
    float2 wv = *(const float2*)(w + t * 2);
    float2 bv = *(const float2*)(b + t * 2);
    float o0 = (v.x - mu) * rs * wv.x + bv.x;
    float o1 = (v.y - mu) * rs * wv.y + bv.y;
    u32 pack = (u32)f2bf(o0) | ((u32)f2bf(o1) << 16);
    *(u32*)(out + (size_t)row * 512 + t * 2) = pack;
}

// ---------------------------------------------------------------------------
// m97-style MFMA GEMM: C[M,N] = A[M,K](bf16) * BT[N,K]^T(bf16) + bias(fp32)
// 128x128 tile, 4 waves (each 64x64), global_load_lds 16B staging.
// MODE 1: bf16 out | 2: fp32 out = acc + res | 4: bf16 head-major
//   MODE 4 (N=1024): out[((b*16 + col/64)*2048 + n)*64 + col%64], q cols<512
//   use bias for cols<512, bias2 for cols>=512.
template <int MODE>
__global__ __launch_bounds__(256) void gemm128(const u16* __restrict__ A,
                                               const u16* __restrict__ BT,
                                               const float* __restrict__ bias,
                                               const float* __restrict__ bias2,
                                               const float* __restrict__ res,
                                               float* __restrict__ outf,
                                               u16* __restrict__ outb,
                                               int M, int N, int K) {
    __shared__ u16 As[128 * 32];   // row-major [128][32], unpadded (gl2lds order)
    __shared__ u16 Bs[128 * 32];
    int t = threadIdx.x;
    int wave = t >> 6, lane = t & 63, quad = lane >> 4, l16 = lane & 15;
    int m0 = blockIdx.x * 128, n0 = blockIdx.y * 128;
    int wm = (wave >> 1) * 64, wn = (wave & 1) * 64;
    f32x4 acc[4][4];
#pragma unroll
    for (int i = 0; i < 4; i++)
#pragma unroll
        for (int j = 0; j < 4; j++) acc[i][j] = (f32x4){0.f, 0.f, 0.f, 0.f};
    // staging: wave w stages rows [w*32, w*32+32) of both tiles; 16 rows/instr,
    // lane i -> row i>>2, col (i&3)*8 (LDS dst = base + i*16B, matches row*32+col)
    const u16* Ag = A + (size_t)(m0 + wave * 32 + (lane >> 2)) * K + (lane & 3) * 8;
    const u16* Bg = BT + (size_t)(n0 + wave * 32 + (lane >> 2)) * K + (lane & 3) * 8;
    u16* Al = As + wave * 32 * 32;
    u16* Bl = Bs + wave * 32 * 32;
    const size_t rstep = (size_t)16 * K;
    for (int k0 = 0; k0 < K; k0 += 32) {
        __syncthreads();
        gl2lds16(Ag + k0, Al);
        gl2lds16(Ag + k0 + rstep, Al + 16 * 32);
        gl2lds16(Bg + k0, Bl);
        gl2lds16(Bg + k0 + rstep, Bl + 16 * 32);
        asm volatile("s_waitcnt vmcnt(0)" ::: "memory");
        __syncthreads();
        bf16x8 a[4], b[4];
#pragma unroll
        for (int i = 0; i < 4; i++) {
            a[i] = *(const bf16x8*)&As[(wm + i * 16 + l16) * 32 + quad * 8];
            b[i] = *(const bf16x8*)&Bs[(wn + i * 16 + l16) * 32 + quad * 8];
        }
#pragma unroll
        for (int i = 0; i < 4; i++)
#pragma unroll
            for (int j = 0; j < 4; j++)
                acc[i][j] = __builtin_amdgcn_mfma_f32_16x16x32_bf16(a[i], b[j], acc[i][j], 0, 0, 0);
    }
    // epilogue: C/D 16x16 layout col=l16, row=quad*4+r
    int row_base = m0 + wm + quad * 4;
    int col_base = n0 + wn + l16;
#pragma unroll
    for (int j = 0; j < 4; j++) {
        int col = col_base + j * 16;
        float bv;
        if (MODE == 4) bv = (col < 512) ? bias[col] : bias2[col - 512];
        else bv = bias[col];
#pragma unroll
        for (int i = 0; i < 4; i++) {
#pragma unroll
            for (int r = 0; r < 4; r++) {
                int row = row_base + i * 16 + r;
                float val = acc[i][j][r] + bv;
                if (MODE == 4) {
                    int bb = row >> 11, n = row & 2047, hh = col >> 6, d = col & 63;
                    outb[((size_t)(bb * 16 + hh) * 2048 + n) * 64 + d] = f2bf(val);
                } else if (MODE == 1) {
                    outb[(size_t)row * N + col] = f2bf(val);
                } else {
                    size_t idx = (size_t)row * N + col;
                    outf[idx] = val + res[idx];
                }
            }
        }
    }
}

// ---------------------------------------------------------------------------
// AA[tok] = 0.125 * sum_d qv[tok][d]^2 over the whole qv buffer (131072 rows)
__global__ __launch_bounds__(256) void aa_kernel(const u16* __restrict__ q,
                                                 float* __restrict__ aa) {
    int t = threadIdx.x;
    int tok = blockIdx.x * 32 + (t >> 3);
    int l8 = t & 7;
    const u16* row = q + (size_t)tok * 64 + l8 * 8;
    uint4 u = *(const uint4*)row;
    u32 c[4] = {u.x, u.y, u.z, u.w};
    float s = 0.f;
#pragma unroll
    for (int k = 0; k < 4; k++) {
        float a = bf2f((u16)(c[k] & 0xffff));
        float b = bf2f((u16)(c[k] >> 16));
        s += a * a + b * b;
    }
    s += __shfl_xor(s, 1); s += __shfl_xor(s, 2); s += __shfl_xor(s, 4);
    if (l8 == 0) aa[tok] = s * 0.125f;
}

// ---------------------------------------------------------------------------
// MFMA flash L2-attention, static-max softmax.
// qv head-major bf16 [(b*16+hh)][2048][64]: q at hh<8, v at hh>=8.
// p = exp(0.25*AB - aas_j - aas_i) (row max is exactly 0 at j=i); no online max.
__global__ __launch_bounds__(256) void attn_mfma(const u16* __restrict__ qv,
                                                 const float* __restrict__ aas,
                                                 u16* __restrict__ out) {
    __shared__ u16 Qj[64][72];   // j-token rows (B operand for S)
    __shared__ u16 VT[64][72];   // V^T [d][j]  (B operand for PV)
    __shared__ u16 Pl[64][72];   // P rows (A operand for PV; wave-local regions)
    int itile = blockIdx.x, bh = blockIdx.y;
    int b = bh >> 3, h = bh & 7;
    const u16* qb = qv + (size_t)(b * 16 + h) * 2048 * 64;
    const u16* vb = qv + (size_t)(b * 16 + 8 + h) * 2048 * 64;
    const float* aab = aas + (size_t)(b * 16 + h) * 2048;
    int t = threadIdx.x;
    int wave = t >> 6, lane = t & 63, quad = lane >> 4, l16 = lane & 15;
    // Qi A-fragments (fixed): row = i, k = d
    int irow = itile * 64 + wave * 16 + l16;
    bf16x8 qa0 = *(const bf16x8*)(qb + (size_t)irow * 64 + quad * 8);
    bf16x8 qa1 = *(const bf16x8*)(qb + (size_t)irow * 64 + 32 + quad * 8);
    float ci[4];
    {
        int r0 = itile * 64 + wave * 16 + quad * 4;
#pragma unroll
        for (int r = 0; r < 4; r++) ci[r] = aab[r0 + r];
    }
    f32x4 O0 = {0.f,0.f,0.f,0.f}, O1 = {0.f,0.f,0.f,0.f};
    f32x4 O2 = {0.f,0.f,0.f,0.f}, O3 = {0.f,0.f,0.f,0.f};
    float lrow[4] = {0.f, 0.f, 0.f, 0.f};
    int sr = t >> 2, sc = (t & 3) * 16;   // Qj staging
    int jp = t & 31, dc = t >> 5;         // VT pair-transpose staging

    for (int j0 = 0; j0 < 2048; j0 += 64) {
        __syncthreads();   // prior iteration's Qj/VT reads complete
        {   // stage Qj rows
            const u16* src = qb + (size_t)(j0 + sr) * 64 + sc;
            uint4 a = *(const uint4*)src;
            uint4 bq = *(const uint4*)(src + 8);
            *(uint4*)&Qj[sr][sc] = a;
            *(uint4*)&Qj[sr][sc + 8] = bq;
        }
        {   // stage V^T: rows j0+2jp, j0+2jp+1, d = dc*8..+7
            const u16* r0 = vb + (size_t)(j0 + 2 * jp) * 64 + dc * 8;
            uint4 u0 = *(const uint4*)r0;
            uint4 u1 = *(const uint4*)(r0 + 64);
            u32 c0[4] = {u0.x, u0.y, u0.z, u0.w};
            u32 c1[4] = {u1.x, u1.y, u1.z, u1.w};
#pragma unroll
            for (int k = 0; k < 8; k++) {
                u32 lo = (k & 1) ? (c0[k >> 1] >> 16) : (c0[k >> 1] & 0xffff);
                u32 hi = (k & 1) ? (c1[k >> 1] >> 16) : (c1[k >> 1] & 0xffff);
                *(u32*)&VT[dc * 8 + k][2 * jp] = lo | (hi << 16);
            }
        }
        float aaj0 = aab[j0 + l16];
        float aaj1 = aab[j0 + 16 + l16];
        float aaj2 = aab[j0 + 32 + l16];
        float aaj3 = aab[j0 + 48 + l16];
        __syncthreads();
        // ---- S = Qi . Qj^T ----
        f32x4 s0 = {0.f,0.f,0.f,0.f}, s1 = {0.f,0.f,0.f,0.f};
        f32x4 s2 = {0.f,0.f,0.f,0.f}, s3 = {0.f,0.f,0.f,0.f};
        {
            bf16x8 b0 = *(const bf16x8*)&Qj[l16][quad * 8];
            bf16x8 b0b = *(const bf16x8*)&Qj[l16][32 + quad * 8];
            s0 = __builtin_amdgcn_mfma_f32_16x16x32_bf16(qa0, b0, s0, 0, 0, 0);
            s0 = __builtin_amdgcn_mfma_f32_16x16x32_bf16(qa1, b0b, s0, 0, 0, 0);
            bf16x8 b1 = *(const bf16x8*)&Qj[16 + l16][quad * 8];
            bf16x8 b1b = *(const bf16x8*)&Qj[16 + l16][32 + quad * 8];
            s1 = __builtin_amdgcn_mfma_f32_16x16x32_bf16(qa0, b1, s1, 0, 0, 0);
            s1 = __builtin_amdgcn_mfma_f32_16x16x32_bf16(qa1, b1b, s1, 0, 0, 0);
            bf16x8 b2 = *(const bf16x8*)&Qj[32 + l16][quad * 8];
            bf16x8 b2b = *(const bf16x8*)&Qj[32 + l16][32 + quad * 8];
            s2 = __builtin_amdgcn_mfma_f32_16x16x32_bf16(qa0, b2, s2, 0, 0, 0);
            s2 = __builtin_amdgcn_mfma_f32_16x16x32_bf16(qa1, b2b, s2, 0, 0, 0);
            bf16x8 b3 = *(const bf16x8*)&Qj[48 + l16][quad * 8];
            bf16x8 b3b = *(const bf16x8*)&Qj[48 + l16][32 + quad * 8];
            s3 = __builtin_amdgcn_mfma_f32_16x16x32_bf16(qa0, b3, s3, 0, 0, 0);
            s3 = __builtin_amdgcn_mfma_f32_16x16x32_bf16(qa1, b3b, s3, 0, 0, 0);
        }
        // ---- p = exp(s*0.25 - aaj - ci); accumulate per-lane l; stage P ----
#pragma unroll
        for (int r = 0; r < 4; r++) {
            float p0 = __expf(s0[r] * 0.25f - aaj0 - ci[r]);
            float p1 = __expf(s1[r] * 0.25f - aaj1 - ci[r]);
            float p2 = __expf(s2[r] * 0.25f - aaj2 - ci[r]);
            float p3 = __expf(s3[r] * 0.25f - aaj3 - ci[r]);
            lrow[r] += p0 + p1 + p2 + p3;
            int prow = wave * 16 + quad * 4 + r;
            Pl[prow][l16] = f2bf(p0);
            Pl[prow][16 + l16] = f2bf(p1);
            Pl[prow][32 + l16] = f2bf(p2);
            Pl[prow][48 + l16] = f2bf(p3);
        }
        // ---- O += P @ V (wave-local Pl; no barrier needed) ----
        {
            bf16x8 pa0 = *(const bf16x8*)&Pl[wave * 16 + l16][quad * 8];
            bf16x8 pa1 = *(const bf16x8*)&Pl[wave * 16 + l16][32 + quad * 8];
            bf16x8 vb0 = *(const bf16x8*)&VT[l16][quad * 8];
            bf16x8 vb0b = *(const bf16x8*)&VT[l16][32 + quad * 8];
            O0 = __builtin_amdgcn_mfma_f32_16x16x32_bf16(pa0, vb0, O0, 0, 0, 0);
            O0 = __builtin_amdgcn_mfma_f32_16x16x32_bf16(pa1, vb0b, O0, 0, 0, 0);
            bf16x8 vb1 = *(const bf16x8*)&VT[16 + l16][quad * 8];
            bf16x8 vb1b = *(const bf16x8*)&VT[16 + l16][32 + quad * 8];
            O1 = __builtin_amdgcn_mfma_f32_16x16x32_bf16(pa0, vb1, O1, 0, 0, 0);
            O1 = __builtin_amdgcn_mfma_f32_16x16x32_bf16(pa1, vb1b, O1, 0, 0, 0);
            bf16x8 vb2 = *(const bf16x8*)&VT[32 + l16][quad * 8];
            bf16x8 vb2b = *(const bf16x8*)&VT[32 + l16][32 + quad * 8];
            O2 = __builtin_amdgcn_mfma_f32_16x16x32_bf16(pa0, vb2, O2, 0, 0, 0);
            O2 = __builtin_amdgcn_mfma_f32_16x16x32_bf16(pa1, vb2b, O2, 0, 0, 0);
            bf16x8 vb3 = *(const bf16x8*)&VT[48 + l16][quad * 8];
            bf16x8 vb3b = *(const bf16x8*)&VT[48 + l16][32 + quad * 8];
            O3 = __builtin_amdgcn_mfma_f32_16x16x32_bf16(pa0, vb3, O3, 0, 0, 0);
            O3 = __builtin_amdgcn_mfma_f32_16x16x32_bf16(pa1, vb3b, O3, 0, 0, 0);
        }
    }
    // epilogue: reduce l across the 16 lanes sharing each row, then write
    int bb = bh >> 3, hh = bh & 7;
#pragma unroll
    for (int r = 0; r < 4; r++) {
        float s = lrow[r];
        s += __shfl_xor(s, 1); s += __shfl_xor(s, 2);
        s += __shfl_xor(s, 4); s += __shfl_xor(s, 8);
        float inv = 1.f / s;
        size_t row = (size_t)(bb * 2048 + itile * 64 + wave * 16 + quad * 4 + r);
        u16* o = out + row * 512 + hh * 64 + l16;
        o[0] = f2bf(O0[r] * inv);
        o[16] = f2bf(O1[r] * inv);
        o[32] = f2bf(O2[r] * inv);
        o[48] = f2bf(O3[r] * inv);
    }
}

// ---------------------------------------------------------------------------
// GEGLU: g[m,c] = h[m,c] * gelu(h[m,2048+c]),  h [8192][4096] bf16
__global__ __launch_bounds__(256) void geglu_kernel(const u16* __restrict__ h,
                                                    u16* __restrict__ g) {
    size_t i = ((size_t)blockIdx.x * 256 + threadIdx.x) * 4;
    size_t m = i >> 11;
    int c = (int)(i & 2047);
    const u16* p = h + m * 4096 + c;
    uint2 ua = *(const uint2*)p;
    uint2 ug = *(const uint2*)(p + 2048);
    float a0 = bf2f((u16)(ua.x & 0xffff)), a1 = bf2f((u16)(ua.x >> 16));
    float a2 = bf2f((u16)(ua.y & 0xffff)), a3 = bf2f((u16)(ua.y >> 16));
    float g0 = bf2f((u16)(ug.x & 0xffff)), g1 = bf2f((u16)(ug.x >> 16));
    float g2 = bf2f((u16)(ug.y & 0xffff)), g3 = bf2f((u16)(ug.y >> 16));
    float r0 = a0 * gelu_exact(g0);
    float r1 = a1 * gelu_exact(g1);
    float r2 = a2 * gelu_exact(g2);
    float r3 = a3 * gelu_exact(g3);
    uint2 o;
    o.x = (u32)f2bf(r0) | ((u32)f2bf(r1) << 16);
    o.y = (u32)f2bf(r2) | ((u32)f2bf(r3) << 16);
    *(uint2*)(g + m * 2048 + c) = o;
}

// ---------------------------------------------------------------------------
extern "C" void kernel_launch(void* const* d_in, const int* in_sizes, int n_in,
                              void* d_out, int out_size, void* d_ws, size_t ws_size,
                              hipStream_t stream) {
    const float* x      = (const float*)d_in[0];
    const float* sa_w   = (const float*)d_in[1];
    const float* sa_b   = (const float*)d_in[2];
    const float* ca_w   = (const float*)d_in[3];
    const float* ca_b   = (const float*)d_in[4];
    const float* ffn_w  = (const float*)d_in[5];
    const float* ffn_b  = (const float*)d_in[6];
    const float* a1_wq  = (const float*)d_in[7];
    const float* a1_bq  = (const float*)d_in[8];
    const float* a1_wv  = (const float*)d_in[9];
    const float* a1_bv  = (const float*)d_in[10];
    const float* a1_wo  = (const float*)d_in[11];
    const float* a1_bo  = (const float*)d_in[12];
    const float* a2_wq  = (const float*)d_in[13];
    const float* a2_bq  = (const float*)d_in[14];
    const float* a2_wv  = (const float*)d_in[15];
    const float* a2_bv  = (const float*)d_in[16];
    const float* a2_wo  = (const float*)d_in[17];
    const float* a2_bo  = (const float*)d_in[18];
    const float* ff_w1  = (const float*)d_in[19];
    const float* ff_b1  = (const float*)d_in[20];
    const float* ff_w2  = (const float*)d_in[21];
    const float* ff_b2  = (const float*)d_in[22];

    char* ws = (char*)d_ws;
    const size_t MB = 1ull << 20;
    float* x_res   = (float*)(ws);              // 16 MB fp32 residual stream
    u16* xn        = (u16*)(ws + 16 * MB);      // 8 MB normed activations (bf16)
    u16* wT_a1qv   = (u16*)(ws + 24 * MB);      // 1 MB [1024][512] (wq^T | wv^T)
    u16* wT_a2qv   = (u16*)(ws + 25 * MB);      // 1 MB
    u16* wT_a1o    = (u16*)(ws + 26 * MB);      // 0.5 MB [512][512]
    u16* wT_a2o    = (u16*)(ws + 26 * MB + 512 * 1024);
    u16* wT_ff1    = (u16*)(ws + 27 * MB);      // 4 MB [4096][512]
    u16* wT_ff2    = (u16*)(ws + 31 * MB);      // 2 MB [512][2048]
    // attn-phase buffers (overlap with ffn-phase hbuf)
    u16* qvhm      = (u16*)(ws + 34 * MB);      // 16 MB bf16 [(b*16+hh)][2048][64]
    float* aab     = (float*)(ws + 50 * MB);    // 512 KB (pre-scaled AA)
    u16* attn_o    = (u16*)(ws + 51 * MB);      // 8 MB bf16 [8192][512]
    // ffn-phase buffers
    u16* hbuf      = (u16*)(ws + 34 * MB);      // 64 MB [8192][4096] bf16
    u16* gbuf      = (u16*)(ws + 98 * MB);      // 32 MB [8192][2048] bf16

    (void)in_sizes; (void)n_in; (void)out_size; (void)ws_size;

    // weight transposes (fp32 -> bf16 [N][K]); q|v concatenated
    transpose_f32_bf16<<<dim3(16, 16), 256, 0, stream>>>(a1_wq, wT_a1qv, 512, 512);
    transpose_f32_bf16<<<dim3(16, 16), 256, 0, stream>>>(a1_wv, wT_a1qv + 512 * 512, 512, 512);
    transpose_f32_bf16<<<dim3(16, 16), 256, 0, stream>>>(a2_wq, wT_a2qv, 512, 512);
    transpose_f32_bf16<<<dim3(16, 16), 256, 0, stream>>>(a2_wv, wT_a2qv + 512 * 512, 512, 512);
    transpose_f32_bf16<<<dim3(16, 16), 256, 0, stream>>>(a1_wo, wT_a1o, 512, 512);
    transpose_f32_bf16<<<dim3(16, 16), 256, 0, stream>>>(a2_wo, wT_a2o, 512, 512);
    transpose_f32_bf16<<<dim3(128, 16), 256, 0, stream>>>(ff_w1, wT_ff1, 512, 4096);
    transpose_f32_bf16<<<dim3(16, 64), 256, 0, stream>>>(ff_w2, wT_ff2, 2048, 512);

    // === attention 1 (self) ===
    ln_kernel<<<8192, 256, 0, stream>>>(x, sa_w, sa_b, xn);
    gemm128<4><<<dim3(64, 8), 256, 0, stream>>>(xn, wT_a1qv, a1_bq, a1_bv, nullptr, nullptr, qvhm, 8192, 1024, 512);
    aa_kernel<<<4096, 256, 0, stream>>>(qvhm, aab);
    attn_mfma<<<dim3(32, 32), 256, 0, stream>>>(qvhm, aab, attn_o);
    gemm128<2><<<dim3(64, 4), 256, 0, stream>>>(attn_o, wT_a1o, a1_bo, nullptr, x, x_res, nullptr, 8192, 512, 512);

    // === attention 2 ("cross", k=q, v from x) ===
    ln_kernel<<<8192, 256, 0, stream>>>(x_res, ca_w, ca_b, xn);
    gemm128<4><<<dim3(64, 8), 256, 0, stream>>>(xn, wT_a2qv, a2_bq, a2_bv, nullptr, nullptr, qvhm, 8192, 1024, 512);
    aa_kernel<<<4096, 256, 0, stream>>>(qvhm, aab);
    attn_mfma<<<dim3(32, 32), 256, 0, stream>>>(qvhm, aab, attn_o);
    gemm128<2><<<dim3(64, 4), 256, 0, stream>>>(attn_o, wT_a2o, a2_bo, nullptr, x_res, x_res, nullptr, 8192, 512, 512);

    // === GEGLU FFN ===
    ln_kernel<<<8192, 256, 0, stream>>>(x_res, ffn_w, ffn_b, xn);
    gemm128<1><<<dim3(64, 32), 256, 0, stream>>>(xn, wT_ff1, ff_b1, nullptr, nullptr, nullptr, hbuf, 8192, 4096, 512);
    geglu_kernel<<<16384, 256, 0, stream>>>(hbuf, gbuf);
    gemm128<2><<<dim3(64, 4), 256, 0, stream>>>(gbuf, wT_ff2, ff_b2, nullptr, x_res, (float*)d_out, nullptr, 8192, 512, 2048);
}